// Round 10
// baseline (332.800 us; speedup 1.0000x reference)
//
#include <hip/hip_runtime.h>
#include <hip/hip_bf16.h>

typedef __attribute__((ext_vector_type(8))) short bf16x8;
typedef __attribute__((ext_vector_type(4))) float f32x4;

static __device__ __forceinline__ unsigned short f2bf(float f){
  __hip_bfloat16 h = __float2bfloat16(f);
  return __builtin_bit_cast(unsigned short, h);
}
static __device__ __forceinline__ unsigned int pk2(float a, float b){
  return (unsigned int)f2bf(a) | ((unsigned int)f2bf(b) << 16);
}
static __device__ __forceinline__ float bf2f(unsigned short h){
  return __uint_as_float(((unsigned int)h) << 16);
}
static __device__ __forceinline__ f32x4 mfma16(bf16x8 a, bf16x8 b, f32x4 c){
  return __builtin_amdgcn_mfma_f32_16x16x32_bf16(a, b, c, 0, 0, 0);
}

// ---------------- prep: fold BNs into weights, convert to bf16 ----------------
__global__ void prep_kernel(
    const float* __restrict__ bn_g, const float* __restrict__ bn_b,
    const float* __restrict__ bn_m, const float* __restrict__ bn_v,
    const float* __restrict__ qk_w, const float* __restrict__ qk_b,
    const float* __restrict__ v_w,  const float* __restrict__ v_b,
    const float* __restrict__ ls,   const float* __restrict__ proj_w,
    const float* __restrict__ proj_b,
    const float* __restrict__ bo_g, const float* __restrict__ bo_b,
    const float* __restrict__ bo_m, const float* __restrict__ bo_v,
    unsigned short* __restrict__ Wqkv, unsigned short* __restrict__ Wp,
    float* __restrict__ bqf, float* __restrict__ bpf,
    float* __restrict__ rsf, float* __restrict__ shf)
{
  int g = blockIdx.x * 256 + threadIdx.x;
  if (g < 384){
    const float* wr = (g < 256) ? (qk_w + g * 128) : (v_w + (g - 256) * 128);
    float acc = (g < 256) ? qk_b[g] : v_b[g - 256];
    for (int c = 0; c < 128; c++){
      float inv = bn_g[c] * rsqrtf(bn_v[c] + 1e-5f);
      float sh  = bn_b[c] - bn_m[c] * inv;
      float wv  = wr[c];
      Wqkv[g * 128 + c] = f2bf(wv * inv);
      acc += wv * sh;
    }
    bqf[g] = acc;
  } else if (g < 512){
    int o = g - 384;
    float invo = bo_g[o] * rsqrtf(bo_v[o] + 1e-5f);
    for (int c = 0; c < 128; c++)
      Wp[o * 128 + c] = f2bf(proj_w[o * 128 + c] * invo);
    bpf[o] = (proj_b[o] - bo_m[o]) * invo + bo_b[o];
    rsf[o] = invo;
    if (o < 4)
      shf[o] = expf(fminf(ls[o], 4.6051701859880914f)) * 0.17677669529663687f; // /sqrt(32)
  }
}

// ---------------- kernel A: x fp32 [n][c][t][v] -> xb bf16 tile image ----------------
// tile (n,v): 64 rows (t) x 256B; 16B chunk u of row t holds c = (u ^ (t&7))*8 .. +7
// v2: 4-t slabs (grid 4096), LDS 27200B -> 6 blocks/CU; per-row XOR column swizzle in LDS
__global__ __launch_bounds__(256) void pack_x(const float* __restrict__ x,
                                              unsigned short* __restrict__ xb)
{
  __shared__ __align__(16) unsigned short tile[100][136];  // row = lt*25+vv, col swizzled by 8*(row&7)
  int n = blockIdx.x >> 4;
  int slab = blockIdx.x & 15;
  int t0 = slab * 4;
  int tid = threadIdx.x;
  const float* xn = x + (long)n * 204800 + (long)t0 * 25;
  for (int k = 0; k < 13; k++){
    int idx = tid + k * 256;            // 3200 float4s: c*25 + r4
    if (idx < 3200){
      int c  = idx / 25;
      int r4 = idx - c * 25;
      float4 f = *((const float4*)(xn + (long)c * 1600 + r4 * 4));
      int r0 = r4 * 4;
      tile[r0+0][c ^ (8*((r0+0)&7))] = f2bf(f.x);
      tile[r0+1][c ^ (8*((r0+1)&7))] = f2bf(f.y);
      tile[r0+2][c ^ (8*((r0+2)&7))] = f2bf(f.z);
      tile[r0+3][c ^ (8*((r0+3)&7))] = f2bf(f.w);
    }
  }
  __syncthreads();
  for (int k = 0; k < 7; k++){
    int idx = tid + k * 256;            // 1600 uint4s: r*16 + u
    if (idx < 1600){
      int r  = idx >> 4;                 // lt*25+vv
      int u  = idx & 15;
      int lt = r / 25;
      int vv = r - lt * 25;
      int t7 = (t0 & 4) + lt;            // t&7 (t0 multiple of 4)
      int c0 = (u ^ t7) * 8;
      uint4 d = *((const uint4*)&tile[r][c0 ^ (8*(r&7))]);
      *((uint4*)(xb + ((long)(n * 25 + vv) * 64 + t0 + lt) * 128 + u * 8)) = d;
    }
  }
}

// ---------------- kernel C: ob bf16 tile image -> out fp32 [n][c][t][v] ----------------
__global__ __launch_bounds__(256) void unpack_out(const unsigned short* __restrict__ ob,
                                                  float* __restrict__ out)
{
  __shared__ __align__(16) unsigned short tile[100][136];
  int n = blockIdx.x >> 4;
  int slab = blockIdx.x & 15;
  int t0 = slab * 4;
  int tid = threadIdx.x;
  for (int k = 0; k < 7; k++){
    int idx = tid + k * 256;
    if (idx < 1600){
      int r  = idx >> 4;
      int u  = idx & 15;
      int lt = r / 25;
      int vv = r - lt * 25;
      uint4 d = *((const uint4*)(ob + ((long)(n * 25 + vv) * 64 + t0 + lt) * 128 + u * 8));
      int t7 = (t0 & 4) + lt;
      int c0 = (u ^ t7) * 8;
      *((uint4*)&tile[r][c0 ^ (8*(r&7))]) = d;
    }
  }
  __syncthreads();
  float* on = out + (long)n * 204800 + (long)t0 * 25;
  for (int k = 0; k < 13; k++){
    int idx = tid + k * 256;
    if (idx < 3200){
      int c  = idx / 25;
      int r4 = idx - c * 25;
      int r0 = r4 * 4;
      float4 f;
      f.x = bf2f(tile[r0+0][c ^ (8*((r0+0)&7))]);
      f.y = bf2f(tile[r0+1][c ^ (8*((r0+1)&7))]);
      f.z = bf2f(tile[r0+2][c ^ (8*((r0+2)&7))]);
      f.w = bf2f(tile[r0+3][c ^ (8*((r0+3)&7))]);
      *((float4*)(on + (long)c * 1600 + r4 * 4)) = f;
    }
  }
}

// ---------------- kernel B: fused compute v6 (v5 + banded no-max softmax) ----------------
// LDS (bytes):
//  RA 0..16383      : x tile image [64 t][256B] -> vT [128 d][128B] -> out staging image
//  RB 16384..49151  : per-head slot 8192B: {q|k} rows [64 t][128B] -> attn [64][128B] ; ao [64][136] ushorts after bar B
//  consts 49152..53759
#define B_RA    0
#define B_RB    16384
#define B_BQ    49152
#define B_BP    50688
#define B_RS    51200
#define B_SH    51712
#define B_BIAS  51728
#define B_TOTAL 53760

__global__ __launch_bounds__(256, 3) void fused_compute(
    const unsigned short* __restrict__ xb,
    const unsigned short* __restrict__ Wqkv,
    const unsigned short* __restrict__ Wp,
    const float* __restrict__ bqf,
    const float* __restrict__ bpf,
    const float* __restrict__ rsf,
    const float* __restrict__ shf,
    const float* __restrict__ relb,
    unsigned short* __restrict__ ob)
{
  __shared__ __align__(16) char smem[B_TOTAL];
  char* ra = smem + B_RA;
  float* c_bq   = (float*)(smem + B_BQ);
  float* c_bp   = (float*)(smem + B_BP);
  float* c_rs   = (float*)(smem + B_RS);
  float* c_sh   = (float*)(smem + B_SH);
  float* c_bias = (float*)(smem + B_BIAS);

  int bid = blockIdx.x;
  int swz = (bid & 7) * 800 + (bid >> 3);   // XCD-bijective (6400 % 8 == 0)
  long tileoff = (long)swz * 8192;          // ushort offset of 16KB tile
  int tid  = threadIdx.x;
  int lane = tid & 63;
  int w    = tid >> 6;
  int h    = w;                              // wave = head
  int l4   = lane >> 4;
  int l15  = lane & 15;

  char* qkh = smem + B_RB + h * 8192;        // [64 t][128B]: q bytes 0..63, k 64..127 (pre-XOR)

  // ---- phase 1: consts + x tile -> RA (coalesced b128) ----
  for (int i = tid; i < 384; i += 256) c_bq[i] = bqf[i];
  if (tid < 128){ c_bp[tid] = bpf[tid]; c_rs[tid] = rsf[tid]; }
  if (tid < 4) c_sh[tid] = shf[tid];
  for (int i = tid; i < 508; i += 256) c_bias[i] = relb[i];
  {
    const uint4* src = (const uint4*)(xb + tileoff);
    uint4* dst = (uint4*)ra;
    #pragma unroll
    for (int i = 0; i < 4; i++) dst[tid + i * 256] = src[tid + i * 256];
  }
  __syncthreads();   // bar A

  const f32x4 zero4 = {0.f, 0.f, 0.f, 0.f};
  uint2 resid[2][4];

  // ---- phase 2a: q/k GEMM (acc pressure 64 VGPRs), normalize, write to RB ----
  {
    int rb[4] = {32*h, 32*h + 16, 128 + 32*h, 128 + 32*h + 16};
    f32x4 acc[4][4];
    #pragma unroll
    for (int m = 0; m < 4; m++)
      #pragma unroll
      for (int nt = 0; nt < 4; nt++) acc[m][nt] = zero4;
    #pragma unroll
    for (int ks = 0; ks < 4; ks++){
      int ko = ks * 32 + l4 * 8;
      bf16x8 a[4], b[4];
      #pragma unroll
      for (int m = 0; m < 4; m++)
        a[m] = *((const bf16x8*)(Wqkv + (rb[m] + l15) * 128 + ko));
      #pragma unroll
      for (int nt = 0; nt < 4; nt++){
        int row = nt * 16 + l15;
        b[nt] = *((const bf16x8*)(ra + row * 256 + ((ko * 2) ^ ((row & 7) << 4))));
      }
      #pragma unroll
      for (int m = 0; m < 4; m++)
        #pragma unroll
        for (int nt = 0; nt < 4; nt++)
          acc[m][nt] = mfma16(a[m], b[nt], acc[m][nt]);
    }
    // bias (C layout: col t = l15, row = l4*4 + r within each 16-row tile)
    #pragma unroll
    for (int m = 0; m < 4; m++)
      #pragma unroll
      for (int nt = 0; nt < 4; nt++)
        #pragma unroll
        for (int r = 0; r < 4; r++)
          acc[m][nt][r] += c_bq[rb[m] + l4 * 4 + r];

    // in-register q/k normalization (sum over d via l4-group shuffle)
    #pragma unroll
    for (int nt = 0; nt < 4; nt++){
      float ssq = 0.f, ssk = 0.f;
      #pragma unroll
      for (int r = 0; r < 4; r++){
        ssq += acc[0][nt][r] * acc[0][nt][r] + acc[1][nt][r] * acc[1][nt][r];
        ssk += acc[2][nt][r] * acc[2][nt][r] + acc[3][nt][r] * acc[3][nt][r];
      }
      ssq += __shfl_xor(ssq, 16); ssq += __shfl_xor(ssq, 32);
      ssk += __shfl_xor(ssk, 16); ssk += __shfl_xor(ssk, 32);
      float scq = c_sh[h] / fmaxf(sqrtf(ssq), 1e-12f);
      float sck = 1.0f   / fmaxf(sqrtf(ssk), 1e-12f);
      int row = nt * 16 + l15;
      #pragma unroll
      for (int m = 0; m < 2; m++){
        uint2 p;
        p.x = pk2(acc[m][nt][0] * scq, acc[m][nt][1] * scq);
        p.y = pk2(acc[m][nt][2] * scq, acc[m][nt][3] * scq);
        *((uint2*)(qkh + row * 128 + ((m * 32 + l4 * 8) ^ ((row & 7) << 4)))) = p;
      }
      #pragma unroll
      for (int m = 2; m < 4; m++){
        uint2 p;
        p.x = pk2(acc[m][nt][0] * sck, acc[m][nt][1] * sck);
        p.y = pk2(acc[m][nt][2] * sck, acc[m][nt][3] * sck);
        *((uint2*)(qkh + row * 128 + ((64 + (m - 2) * 32 + l4 * 8) ^ ((row & 7) << 4)))) = p;
      }
    }
  }

  // ---- phase 2b: v GEMM (acc pressure 32 VGPRs) + resid extraction; vT overlays RA ----
  {
    int rb4 = 256 + 32 * h, rb5 = 256 + 32 * h + 16;
    f32x4 accv[2][4];
    #pragma unroll
    for (int m = 0; m < 2; m++)
      #pragma unroll
      for (int nt = 0; nt < 4; nt++) accv[m][nt] = zero4;
    #pragma unroll
    for (int ks = 0; ks < 4; ks++){
      int ko = ks * 32 + l4 * 8;
      bf16x8 a0 = *((const bf16x8*)(Wqkv + (rb4 + l15) * 128 + ko));
      bf16x8 a1 = *((const bf16x8*)(Wqkv + (rb5 + l15) * 128 + ko));
      #pragma unroll
      for (int nt = 0; nt < 4; nt++){
        int row = nt * 16 + l15;
        bf16x8 b = *((const bf16x8*)(ra + row * 256 + ((ko * 2) ^ ((row & 7) << 4))));
        accv[0][nt] = mfma16(a0, b, accv[0][nt]);
        accv[1][nt] = mfma16(a1, b, accv[1][nt]);
      }
    }
    // residual extraction (last RA reads) for this thread's phase-6 cells
    #pragma unroll
    for (int mt = 0; mt < 2; mt++)
      #pragma unroll
      for (int nt = 0; nt < 4; nt++){
        int o0 = w * 32 + mt * 16 + l4 * 4;
        int t2 = nt * 16 + l15;
        resid[mt][nt] = *((const uint2*)(ra + t2 * 256 + ((o0 * 2) ^ ((t2 & 7) << 4))));
      }
    __syncthreads();   // bar E: ALL RA reads done -> vT may overlay RA

    // write vT [128 d][128B] over RA, swizzled scalar b16 (with bias)
    #pragma unroll
    for (int m = 0; m < 2; m++)
      #pragma unroll
      for (int nt = 0; nt < 4; nt++)
        #pragma unroll
        for (int r = 0; r < 4; r++){
          int d = h * 32 + m * 16 + l4 * 4 + r;
          float vv = accv[m][nt][r] + c_bq[256 + h * 32 + m * 16 + l4 * 4 + r];
          *((unsigned short*)(ra + d * 128 + ((((nt * 16 + l15) * 2)) ^ ((d & 7) << 4)))) = f2bf(vv);
        }
  }
  __builtin_amdgcn_sched_barrier(0);   // wave-private LDS RAW fence

  // ---- phase 4: score fragments (own-wave LDS, DS in-order per wave) ----
  bf16x8 kf[4], qf[4];
  {
    #pragma unroll
    for (int jt = 0; jt < 4; jt++){
      int row = jt * 16 + l15;
      kf[jt] = *((const bf16x8*)(qkh + row * 128 + ((64 + l4 * 16) ^ ((row & 7) << 4))));
    }
    #pragma unroll
    for (int it = 0; it < 4; it++){
      int row = it * 16 + l15;
      qf[it] = *((const bf16x8*)(qkh + row * 128 + ((l4 * 16) ^ ((row & 7) << 4))));
    }
  }
  __builtin_amdgcn_sched_barrier(0);

  // ---- phase 5a: banded scores^T = K·Q^T (|jt-it|<=1 only), no-max softmax ----
  // justification: q,k are L2-normalized, |score| <= c_sh (<=17.7 capped) + |bias| -> fp32 exp safe;
  // exp(s)/sum(exp(s)) == softmax exactly.
  {
    f32x4 sAcc[4][4];
    #pragma unroll
    for (int jt = 0; jt < 4; jt++)
      #pragma unroll
      for (int it = 0; it < 4; it++) sAcc[jt][it] = zero4;
    #pragma unroll
    for (int jt = 0; jt < 4; jt++)
      #pragma unroll
      for (int it = 0; it < 4; it++)
        if (jt <= it + 1 && it <= jt + 1)
          sAcc[jt][it] = mfma16(kf[jt], qf[it], sAcc[jt][it]);

    #pragma unroll
    for (int it = 0; it < 4; it++){
      int i = it * 16 + l15;
      float sv[16];
      float sum = 0.f;
      #pragma unroll
      for (int jt = 0; jt < 4; jt++){
        if (jt + 1 < it || jt > it + 1) continue;   // fully-masked tile
        #pragma unroll
        for (int r = 0; r < 4; r++){
          int j = jt * 16 + l4 * 4 + r;
          int rel = j - i;
          float s = sAcc[jt][it][r] + c_bias[h * 127 + rel + 63];  // idx in [32,94]+h*127: in bounds
          bool inb = (rel >= -4) && (rel <= 4);
          float p = inb ? __expf(s) : 0.f;
          sv[jt * 4 + r] = p;
          sum += p;
        }
      }
      sum += __shfl_xor(sum, 16);
      sum += __shfl_xor(sum, 32);
      float rs = 1.0f / sum;
      #pragma unroll
      for (int jt = 0; jt < 4; jt++){
        uint2 p;
        if (jt + 1 < it || jt > it + 1){
          p.x = 0u; p.y = 0u;
        } else {
          p.x = pk2(sv[jt*4+0] * rs, sv[jt*4+1] * rs);
          p.y = pk2(sv[jt*4+2] * rs, sv[jt*4+3] * rs);
        }
        *((uint2*)(qkh + i * 128 + ((jt * 32 + l4 * 8) ^ ((i & 7) << 4)))) = p;
      }
    }
  }
  __builtin_amdgcn_sched_barrier(0);

  // ---- PV fragments (own attn rows + own vT rows) ----
  bf16x8 av[2][2], bv2[4][2];
  {
    #pragma unroll
    for (int mt = 0; mt < 2; mt++)
      #pragma unroll
      for (int ks2 = 0; ks2 < 2; ks2++){
        int row = h * 32 + mt * 16 + l15;
        av[mt][ks2] = *((const bf16x8*)(ra + row * 128 + ((ks2 * 64 + l4 * 16) ^ ((row & 7) << 4))));
      }
    #pragma unroll
    for (int it = 0; it < 4; it++)
      #pragma unroll
      for (int ks2 = 0; ks2 < 2; ks2++){
        int row = it * 16 + l15;
        bv2[it][ks2] = *((const bf16x8*)(qkh + row * 128 + ((ks2 * 64 + l4 * 16) ^ ((row & 7) << 4))));
      }
  }
  __syncthreads();   // bar B: all attn/vT-for-PV reads done -> ao may overwrite RB

  // ---- phase 5b: ao[t][c] = (val^T · attn^T)^T ----
  unsigned short* ao = (unsigned short*)(smem + B_RB);   // [64][136]
  {
    f32x4 pAcc[2][4];
    #pragma unroll
    for (int mt = 0; mt < 2; mt++)
      #pragma unroll
      for (int it = 0; it < 4; it++) pAcc[mt][it] = zero4;
    #pragma unroll
    for (int mt = 0; mt < 2; mt++)
      #pragma unroll
      for (int it = 0; it < 4; it++)
        #pragma unroll
        for (int ks2 = 0; ks2 < 2; ks2++)
          pAcc[mt][it] = mfma16(av[mt][ks2], bv2[it][ks2], pAcc[mt][it]);
    #pragma unroll
    for (int mt = 0; mt < 2; mt++)
      #pragma unroll
      for (int it = 0; it < 4; it++){
        int d0 = mt * 16 + l4 * 4;
        int i  = it * 16 + l15;
        uint2 p;
        p.x = pk2(pAcc[mt][it][0], pAcc[mt][it][1]);
        p.y = pk2(pAcc[mt][it][2], pAcc[mt][it][3]);
        *((uint2*)&ao[i * 136 + h * 32 + d0]) = p;
      }
  }
  __syncthreads();   // bar C: ao complete

  // ---- phase 6: proj GEMM + residual(regs) + out-BN, stage into RA image, copy out ----
  {
    f32x4 acc2[2][4];
    #pragma unroll
    for (int mt = 0; mt < 2; mt++)
      #pragma unroll
      for (int nt = 0; nt < 4; nt++) acc2[mt][nt] = zero4;
    #pragma unroll
    for (int ks = 0; ks < 4; ks++){
      int ko = ks * 32 + l4 * 8;
      bf16x8 a2[2], b2[4];
      #pragma unroll
      for (int mt = 0; mt < 2; mt++)
        a2[mt] = *((const bf16x8*)(Wp + (w * 32 + mt * 16 + l15) * 128 + ko));
      #pragma unroll
      for (int nt = 0; nt < 4; nt++)
        b2[nt] = *((const bf16x8*)&ao[(nt * 16 + l15) * 136 + ko]);
      #pragma unroll
      for (int mt = 0; mt < 2; mt++)
        #pragma unroll
        for (int nt = 0; nt < 4; nt++)
          acc2[mt][nt] = mfma16(a2[mt], b2[nt], acc2[mt][nt]);
    }
    #pragma unroll
    for (int mt = 0; mt < 2; mt++)
      #pragma unroll
      for (int nt = 0; nt < 4; nt++){
        int o0 = w * 32 + mt * 16 + l4 * 4;
        int t2 = nt * 16 + l15;
        uint2 rd = resid[mt][nt];
        float r0 = bf2f((unsigned short)(rd.x & 0xFFFFu));
        float r1f = bf2f((unsigned short)(rd.x >> 16));
        float r2 = bf2f((unsigned short)(rd.y & 0xFFFFu));
        float r3 = bf2f((unsigned short)(rd.y >> 16));
        uint2 p;
        p.x = pk2(acc2[mt][nt][0] + c_bp[o0+0] + r0 * c_rs[o0+0],
                  acc2[mt][nt][1] + c_bp[o0+1] + r1f * c_rs[o0+1]);
        p.y = pk2(acc2[mt][nt][2] + c_bp[o0+2] + r2 * c_rs[o0+2],
                  acc2[mt][nt][3] + c_bp[o0+3] + r3 * c_rs[o0+3]);
        *((uint2*)(ra + t2 * 256 + ((o0 * 2) ^ ((t2 & 7) << 4)))) = p;
      }
  }
  __syncthreads();   // bar D
  {
    const uint4* sxl = (const uint4*)ra;
    uint4* obt = (uint4*)(ob + tileoff);
    #pragma unroll
    for (int i = 0; i < 4; i++) obt[tid + i * 256] = sxl[tid + i * 256];
  }
}

// ---------------- fallback: fused scatter kernel (ws too small) ----------------
#define F_X     0
#define F_RB    17408
#define F_VT    58368
#define F_BQ    76800
#define F_BP    78336
#define F_RS    78848
#define F_SH    79360
#define F_BIAS  79376
#define F_TOTAL 81408

__global__ __launch_bounds__(256, 2) void fused_scatter(
    const float* __restrict__ x,
    const unsigned short* __restrict__ Wqkv,
    const unsigned short* __restrict__ Wp,
    const float* __restrict__ bqf,
    const float* __restrict__ bpf,
    const float* __restrict__ rsf,
    const float* __restrict__ shf,
    const float* __restrict__ relb,
    float* __restrict__ out)
{
  __shared__ __align__(16) char smem[F_TOTAL];
  unsigned short* xl   = (unsigned short*)(smem + F_X);
  unsigned short* rbu  = (unsigned short*)(smem + F_RB);
  unsigned short* vT   = (unsigned short*)(smem + F_VT);
  float* c_bq   = (float*)(smem + F_BQ);
  float* c_bp   = (float*)(smem + F_BP);
  float* c_rs   = (float*)(smem + F_RS);
  float* c_sh   = (float*)(smem + F_SH);
  float* c_bias = (float*)(smem + F_BIAS);

  int bid = blockIdx.x;
  int swz = (bid & 7) * 800 + (bid >> 3);
  int n = swz / 25;
  int v = swz - n * 25;
  int tid  = threadIdx.x;
  int lane = tid & 63;
  int w    = tid >> 6;
  int l4   = lane >> 4;
  int l15  = lane & 15;

  for (int i = tid; i < 384; i += 256) c_bq[i] = bqf[i];
  if (tid < 128){ c_bp[tid] = bpf[tid]; c_rs[tid] = rsf[tid]; }
  if (tid < 4) c_sh[tid] = shf[tid];
  for (int i = tid; i < 508; i += 256) c_bias[i] = relb[i];

  {
    const float* xb2 = x + (long)n * 204800 + v;
    int t  = lane;
    int cg = w * 32;
    #pragma unroll
    for (int i = 0; i < 4; i++){
      unsigned int pk[4];
      #pragma unroll
      for (int e = 0; e < 4; e++){
        int c = cg + i * 8 + e * 2;
        pk[e] = pk2(xb2[(long)c * 1600 + t * 25], xb2[(long)(c + 1) * 1600 + t * 25]);
      }
      uint4 q4; q4.x = pk[0]; q4.y = pk[1]; q4.z = pk[2]; q4.w = pk[3];
      *((uint4*)&xl[t * 136 + cg + i * 8]) = q4;
    }
  }
  __syncthreads();

  const f32x4 zero4 = {0.f, 0.f, 0.f, 0.f};

  {
    f32x4 acc[6][4];
    #pragma unroll
    for (int m = 0; m < 6; m++)
      #pragma unroll
      for (int nt = 0; nt < 4; nt++) acc[m][nt] = zero4;
    int Mb = w * 96;
    #pragma unroll
    for (int ks = 0; ks < 4; ks++){
      int ko = ks * 32 + l4 * 8;
      bf16x8 a[6], b[4];
      #pragma unroll
      for (int m = 0; m < 6; m++)
        a[m] = *((const bf16x8*)(Wqkv + (Mb + m * 16 + l15) * 128 + ko));
      #pragma unroll
      for (int nt = 0; nt < 4; nt++)
        b[nt] = *((const bf16x8*)&xl[(nt * 16 + l15) * 136 + ko]);
      #pragma unroll
      for (int m = 0; m < 6; m++)
        #pragma unroll
        for (int nt = 0; nt < 4; nt++)
          acc[m][nt] = mfma16(a[m], b[nt], acc[m][nt]);
    }
    #pragma unroll
    for (int m = 0; m < 6; m++){
      #pragma unroll
      for (int nt = 0; nt < 4; nt++){
        #pragma unroll
        for (int r = 0; r < 4; r++){
          int o  = Mb + m * 16 + l4 * 4 + r;
          int t2 = nt * 16 + l15;
          unsigned short bv = f2bf(acc[m][nt][r] + c_bq[o]);
          if (o < 256){
            rbu[(((o >> 7) * 4 + ((o >> 5) & 3)) * 64 + t2) * 40 + (o & 31)] = bv;
          } else {
            vT[(o - 256) * 72 + t2] = bv;
          }
        }
      }
    }
  }
  __syncthreads();

  {
    #pragma unroll
    for (int rr = 0; rr < 2; rr++){
      int r = tid + rr * 256;
      unsigned short* row = &rbu[r * 40];
      uint4 u0 = *((uint4*)(row + 0));
      uint4 u1 = *((uint4*)(row + 8));
      uint4 u2 = *((uint4*)(row + 16));
      uint4 u3 = *((uint4*)(row + 24));
      unsigned int uu[16] = {u0.x,u0.y,u0.z,u0.w, u1.x,u1.y,u1.z,u1.w,
                             u2.x,u2.y,u2.z,u2.w, u3.x,u3.y,u3.z,u3.w};
      float vals[32];
      float ss = 0.f;
      #pragma unroll
      for (int k2 = 0; k2 < 16; k2++){
        float f0 = bf2f((unsigned short)(uu[k2] & 0xFFFFu));
        float f1 = bf2f((unsigned short)(uu[k2] >> 16));
        vals[2*k2] = f0; vals[2*k2+1] = f1;
        ss += f0 * f0 + f1 * f1;
      }
      float sc = 1.0f / fmaxf(sqrtf(ss), 1e-12f);
      if (r < 256) sc *= c_sh[(r >> 6) & 3];
      #pragma unroll
      for (int k2 = 0; k2 < 16; k2++)
        uu[k2] = pk2(vals[2*k2] * sc, vals[2*k2+1] * sc);
      u0.x=uu[0];u0.y=uu[1];u0.z=uu[2];u0.w=uu[3];
      u1.x=uu[4];u1.y=uu[5];u1.z=uu[6];u1.w=uu[7];
      u2.x=uu[8];u2.y=uu[9];u2.z=uu[10];u2.w=uu[11];
      u3.x=uu[12];u3.y=uu[13];u3.z=uu[14];u3.w=uu[15];
      *((uint4*)(row + 0))  = u0;
      *((uint4*)(row + 8))  = u1;
      *((uint4*)(row + 16)) = u2;
      *((uint4*)(row + 24)) = u3;
    }
  }
  __syncthreads();

  int h = w;
  bf16x8 kf[4], qf[4];
  {
    const unsigned short* kb = &rbu[(256 + h * 64) * 40];
    const unsigned short* qb = &rbu[(h * 64) * 40];
    int ko = l4 * 8;
    #pragma unroll
    for (int jt = 0; jt < 4; jt++)
      kf[jt] = *((const bf16x8*)(kb + (jt * 16 + l15) * 40 + ko));
    #pragma unroll
    for (int it = 0; it < 4; it++)
      qf[it] = *((const bf16x8*)(qb + (it * 16 + l15) * 40 + ko));
  }
  __syncthreads();

  unsigned short* attn = rbu + h * 4608;
  {
    f32x4 sAcc[4][4];
    #pragma unroll
    for (int jt = 0; jt < 4; jt++)
      #pragma unroll
      for (int it = 0; it < 4; it++) sAcc[jt][it] = zero4;
    #pragma unroll
    for (int jt = 0; jt < 4; jt++)
      #pragma unroll
      for (int it = 0; it < 4; it++)
        sAcc[jt][it] = mfma16(kf[jt], qf[it], sAcc[jt][it]);

    #pragma unroll
    for (int it = 0; it < 4; it++){
      int i = it * 16 + l15;
      float sv[16];
      float mx = -1e30f;
      #pragma unroll
      for (int jt = 0; jt < 4; jt++){
        #pragma unroll
        for (int r = 0; r < 4; r++){
          int j = jt * 16 + l4 * 4 + r;
          int rel = j - i;
          float s;
          if (rel < -4 || rel > 4) s = -1e9f;
          else s = sAcc[jt][it][r] + c_bias[h * 127 + rel + 63];
          sv[jt * 4 + r] = s;
          mx = fmaxf(mx, s);
        }
      }
      mx = fmaxf(mx, __shfl_xor(mx, 16));
      mx = fmaxf(mx, __shfl_xor(mx, 32));
      float sum = 0.f;
      #pragma unroll
      for (int k2 = 0; k2 < 16; k2++){
        float p = __expf(sv[k2] - mx);
        sv[k2] = p; sum += p;
      }
      sum += __shfl_xor(sum, 16);
      sum += __shfl_xor(sum, 32);
      float rs = 1.0f / sum;
      #pragma unroll
      for (int jt = 0; jt < 4; jt++)
        #pragma unroll
        for (int r = 0; r < 4; r++)
          attn[i * 72 + (jt * 16 + l4 * 4 + r)] = f2bf(sv[jt * 4 + r] * rs);
    }
  }

  bf16x8 av[2][2], bv2[4][2];
  {
    int ko = l4 * 8;
    #pragma unroll
    for (int mt = 0; mt < 2; mt++)
      #pragma unroll
      for (int ks2 = 0; ks2 < 2; ks2++)
        av[mt][ks2] = *((const bf16x8*)&vT[(h * 32 + mt * 16 + l15) * 72 + ks2 * 32 + ko]);
    #pragma unroll
    for (int it = 0; it < 4; it++)
      #pragma unroll
      for (int ks2 = 0; ks2 < 2; ks2++)
        bv2[it][ks2] = *((const bf16x8*)&attn[(it * 16 + l15) * 72 + ks2 * 32 + ko]);
  }
  __syncthreads();

  unsigned short* ao = rbu;
  {
    f32x4 pAcc[2][4];
    #pragma unroll
    for (int mt = 0; mt < 2; mt++)
      #pragma unroll
      for (int it = 0; it < 4; it++) pAcc[mt][it] = zero4;
    #pragma unroll
    for (int mt = 0; mt < 2; mt++)
      #pragma unroll
      for (int it = 0; it < 4; it++)
        #pragma unroll
        for (int ks2 = 0; ks2 < 2; ks2++)
          pAcc[mt][it] = mfma16(av[mt][ks2], bv2[it][ks2], pAcc[mt][it]);
    #pragma unroll
    for (int mt = 0; mt < 2; mt++)
      #pragma unroll
      for (int it = 0; it < 4; it++)
        #pragma unroll
        for (int r = 0; r < 4; r++){
          int d = mt * 16 + l4 * 4 + r;
          int i = it * 16 + l15;
          ao[i * 136 + h * 32 + d] = f2bf(pAcc[mt][it][r]);
        }
  }
  __syncthreads();

  {
    f32x4 acc2[2][4];
    #pragma unroll
    for (int mt = 0; mt < 2; mt++)
      #pragma unroll
      for (int nt = 0; nt < 4; nt++) acc2[mt][nt] = zero4;
    #pragma unroll
    for (int ks = 0; ks < 4; ks++){
      int ko = ks * 32 + l4 * 8;
      bf16x8 a2[2], b2[4];
      #pragma unroll
      for (int mt = 0; mt < 2; mt++)
        a2[mt] = *((const bf16x8*)(Wp + (w * 32 + mt * 16 + l15) * 128 + ko));
      #pragma unroll
      for (int nt = 0; nt < 4; nt++)
        b2[nt] = *((const bf16x8*)&ao[(nt * 16 + l15) * 136 + ko]);
      #pragma unroll
      for (int mt = 0; mt < 2; mt++)
        #pragma unroll
        for (int nt = 0; nt < 4; nt++)
          acc2[mt][nt] = mfma16(a2[mt], b2[nt], acc2[mt][nt]);
    }
    float* outp = out + (long)n * 204800 + v;
    #pragma unroll
    for (int mt = 0; mt < 2; mt++)
      #pragma unroll
      for (int nt = 0; nt < 4; nt++)
        #pragma unroll
        for (int r = 0; r < 4; r++){
          int o  = w * 32 + mt * 16 + l4 * 4 + r;
          int t2 = nt * 16 + l15;
          float val = acc2[mt][nt][r] + c_bp[o] + bf2f(xl[t2 * 136 + o]) * c_rs[o];
          outp[(long)o * 1600 + t2 * 25] = val;
        }
  }
}

// ---------------- launcher ----------------
extern "C" void kernel_launch(void* const* d_in, const int* in_sizes, int n_in,
                              void* d_out, int out_size, void* d_ws, size_t ws_size,
                              hipStream_t stream)
{
  const float* x     = (const float*)d_in[0];
  const float* bn_g  = (const float*)d_in[1];
  const float* bn_b  = (const float*)d_in[2];
  const float* bn_m  = (const float*)d_in[3];
  const float* bn_v  = (const float*)d_in[4];
  const float* qk_w  = (const float*)d_in[5];
  const float* qk_b  = (const float*)d_in[6];
  const float* v_w   = (const float*)d_in[7];
  const float* v_b   = (const float*)d_in[8];
  const float* ls    = (const float*)d_in[9];
  const float* relb  = (const float*)d_in[10];
  const float* pj_w  = (const float*)d_in[11];
  const float* pj_b  = (const float*)d_in[12];
  const float* bo_g  = (const float*)d_in[13];
  const float* bo_b  = (const float*)d_in[14];
  const float* bo_m  = (const float*)d_in[15];
  const float* bo_v  = (const float*)d_in[16];

  const size_t XB_BYTES = 104857600;   // 6400 * 16384
  const size_t NEED = 2 * XB_BYTES + 98304 + 32768 + 1536 + 512 + 512 + 16;

  char* ws = (char*)d_ws;
  size_t wbase = (ws_size >= NEED) ? (2 * XB_BYTES) : 0;

  unsigned short* Wqkv = (unsigned short*)(ws + wbase);
  unsigned short* Wp   = (unsigned short*)(ws + wbase + 98304);
  float* bqf = (float*)(ws + wbase + 131072);
  float* bpf = (float*)(ws + wbase + 132608);
  float* rsf = (float*)(ws + wbase + 133120);
  float* shf = (float*)(ws + wbase + 133632);

  hipLaunchKernelGGL(prep_kernel, dim3(2), dim3(256), 0, stream,
                     bn_g, bn_b, bn_m, bn_v, qk_w, qk_b, v_w, v_b, ls,
                     pj_w, pj_b, bo_g, bo_b, bo_m, bo_v,
                     Wqkv, Wp, bqf, bpf, rsf, shf);

  if (ws_size >= NEED){
    unsigned short* xb = (unsigned short*)(ws);
    unsigned short* ob = (unsigned short*)(ws + XB_BYTES);
    hipLaunchKernelGGL(pack_x, dim3(4096), dim3(256), 0, stream, x, xb);
    hipLaunchKernelGGL(fused_compute, dim3(6400), dim3(256), 0, stream,
                       xb, Wqkv, Wp, bqf, bpf, rsf, shf, relb, ob);
    hipLaunchKernelGGL(unpack_out, dim3(4096), dim3(256), 0, stream, ob, (float*)d_out);
  } else {
    hipLaunchKernelGGL(fused_scatter, dim3(6400), dim3(256), 0, stream,
                       x, Wqkv, Wp, bqf, bpf, rsf, shf, relb, (float*)d_out);
  }
}

// Round 11
// 298.735 us; speedup vs baseline: 1.1140x; 1.1140x over previous
//
#include <hip/hip_runtime.h>
#include <hip/hip_bf16.h>

typedef __attribute__((ext_vector_type(8))) short bf16x8;
typedef __attribute__((ext_vector_type(4))) float f32x4;

static __device__ __forceinline__ unsigned short f2bf(float f){
  __hip_bfloat16 h = __float2bfloat16(f);
  return __builtin_bit_cast(unsigned short, h);
}
static __device__ __forceinline__ unsigned int pk2(float a, float b){
  return (unsigned int)f2bf(a) | ((unsigned int)f2bf(b) << 16);
}
static __device__ __forceinline__ float bf2f(unsigned short h){
  return __uint_as_float(((unsigned int)h) << 16);
}
static __device__ __forceinline__ f32x4 mfma16(bf16x8 a, bf16x8 b, f32x4 c){
  return __builtin_amdgcn_mfma_f32_16x16x32_bf16(a, b, c, 0, 0, 0);
}

// ---------------- prep body (device): fold BNs into weights, convert to bf16 ----------------
static __device__ __forceinline__ void prep_body(int g,
    const float* __restrict__ bn_g, const float* __restrict__ bn_b,
    const float* __restrict__ bn_m, const float* __restrict__ bn_v,
    const float* __restrict__ qk_w, const float* __restrict__ qk_b,
    const float* __restrict__ v_w,  const float* __restrict__ v_b,
    const float* __restrict__ ls,   const float* __restrict__ proj_w,
    const float* __restrict__ proj_b,
    const float* __restrict__ bo_g, const float* __restrict__ bo_b,
    const float* __restrict__ bo_m, const float* __restrict__ bo_v,
    unsigned short* __restrict__ Wqkv, unsigned short* __restrict__ Wp,
    float* __restrict__ bqf, float* __restrict__ bpf,
    float* __restrict__ rsf, float* __restrict__ shf)
{
  if (g < 384){
    const float* wr = (g < 256) ? (qk_w + g * 128) : (v_w + (g - 256) * 128);
    float acc = (g < 256) ? qk_b[g] : v_b[g - 256];
    for (int c = 0; c < 128; c++){
      float inv = bn_g[c] * rsqrtf(bn_v[c] + 1e-5f);
      float sh  = bn_b[c] - bn_m[c] * inv;
      float wv  = wr[c];
      Wqkv[g * 128 + c] = f2bf(wv * inv);
      acc += wv * sh;
    }
    bqf[g] = acc;
  } else if (g < 512){
    int o = g - 384;
    float invo = bo_g[o] * rsqrtf(bo_v[o] + 1e-5f);
    for (int c = 0; c < 128; c++)
      Wp[o * 128 + c] = f2bf(proj_w[o * 128 + c] * invo);
    bpf[o] = (proj_b[o] - bo_m[o]) * invo + bo_b[o];
    rsf[o] = invo;
    if (o < 4)
      shf[o] = expf(fminf(ls[o], 4.6051701859880914f)) * 0.17677669529663687f; // /sqrt(32)
  }
}

__global__ void prep_kernel(
    const float* __restrict__ bn_g, const float* __restrict__ bn_b,
    const float* __restrict__ bn_m, const float* __restrict__ bn_v,
    const float* __restrict__ qk_w, const float* __restrict__ qk_b,
    const float* __restrict__ v_w,  const float* __restrict__ v_b,
    const float* __restrict__ ls,   const float* __restrict__ proj_w,
    const float* __restrict__ proj_b,
    const float* __restrict__ bo_g, const float* __restrict__ bo_b,
    const float* __restrict__ bo_m, const float* __restrict__ bo_v,
    unsigned short* __restrict__ Wqkv, unsigned short* __restrict__ Wp,
    float* __restrict__ bqf, float* __restrict__ bpf,
    float* __restrict__ rsf, float* __restrict__ shf)
{
  int g = blockIdx.x * 256 + threadIdx.x;
  prep_body(g, bn_g, bn_b, bn_m, bn_v, qk_w, qk_b, v_w, v_b, ls,
            proj_w, proj_b, bo_g, bo_b, bo_m, bo_v, Wqkv, Wp, bqf, bpf, rsf, shf);
}

// ---------------- kernel A: x fp32 [n][c][t][v] -> xb bf16 tile image (+ merged prep) ----------------
// tile (n,v): 64 rows (t) x 256B; 16B chunk u of row t holds c = (u ^ (t&7))*8 .. +7
__global__ __launch_bounds__(256) void pack_x(const float* __restrict__ x,
    unsigned short* __restrict__ xb,
    const float* __restrict__ bn_g, const float* __restrict__ bn_b,
    const float* __restrict__ bn_m, const float* __restrict__ bn_v,
    const float* __restrict__ qk_w, const float* __restrict__ qk_b,
    const float* __restrict__ v_w,  const float* __restrict__ v_b,
    const float* __restrict__ ls,   const float* __restrict__ proj_w,
    const float* __restrict__ proj_b,
    const float* __restrict__ bo_g, const float* __restrict__ bo_b,
    const float* __restrict__ bo_m, const float* __restrict__ bo_v,
    unsigned short* __restrict__ Wqkv, unsigned short* __restrict__ Wp,
    float* __restrict__ bqf, float* __restrict__ bpf,
    float* __restrict__ rsf, float* __restrict__ shf)
{
  __shared__ __align__(16) unsigned short tile[200][136];  // row = lt*25+vv
  int n = blockIdx.x >> 3;
  int slab = blockIdx.x & 7;
  int t0 = slab * 8;
  int tid = threadIdx.x;
  const float* xn = x + (long)n * 204800 + (long)t0 * 25;
  #pragma unroll 5
  for (int k = 0; k < 25; k++){
    int idx = tid + k * 256;          // 6400 float4s
    int c  = idx / 50;
    int r4 = idx - c * 50;
    float4 f = *((const float4*)(xn + (long)c * 1600 + r4 * 4));
    tile[r4*4+0][c] = f2bf(f.x);
    tile[r4*4+1][c] = f2bf(f.y);
    tile[r4*4+2][c] = f2bf(f.z);
    tile[r4*4+3][c] = f2bf(f.w);
  }
  __syncthreads();
  for (int k = 0; k < 13; k++){
    int idx = tid + k * 256;
    if (idx < 3200){
      int r  = idx >> 4;                   // lt*25+vv
      int u  = idx & 15;
      int lt = r / 25;
      int vv = r - lt * 25;
      int c0 = (u ^ lt) * 8;               // (t&7) == lt since t0 % 8 == 0
      uint4 d = *((const uint4*)&tile[r][c0]);
      *((uint4*)(xb + ((long)(n * 25 + vv) * 64 + t0 + lt) * 128 + u * 8)) = d;
    }
  }
  // merged prep: blocks 0 and 1 fold the BNs into weights (ready before fused launch)
  if (blockIdx.x < 2){
    int g = blockIdx.x * 256 + tid;
    prep_body(g, bn_g, bn_b, bn_m, bn_v, qk_w, qk_b, v_w, v_b, ls,
              proj_w, proj_b, bo_g, bo_b, bo_m, bo_v, Wqkv, Wp, bqf, bpf, rsf, shf);
  }
}

// ---------------- kernel C: ob bf16 tile image -> out fp32 [n][c][t][v] ----------------
__global__ __launch_bounds__(256) void unpack_out(const unsigned short* __restrict__ ob,
                                                  float* __restrict__ out)
{
  __shared__ __align__(16) unsigned short tile[200][136];
  int n = blockIdx.x >> 3;
  int slab = blockIdx.x & 7;
  int t0 = slab * 8;
  int tid = threadIdx.x;
  for (int k = 0; k < 13; k++){
    int idx = tid + k * 256;
    if (idx < 3200){
      int r  = idx >> 4;
      int u  = idx & 15;
      int lt = r / 25;
      int vv = r - lt * 25;
      uint4 d = *((const uint4*)(ob + ((long)(n * 25 + vv) * 64 + t0 + lt) * 128 + u * 8));
      int c0 = (u ^ lt) * 8;
      *((uint4*)&tile[r][c0]) = d;
    }
  }
  __syncthreads();
  float* on = out + (long)n * 204800 + (long)t0 * 25;
  #pragma unroll 5
  for (int k = 0; k < 25; k++){
    int idx = tid + k * 256;
    int c  = idx / 50;
    int r4 = idx - c * 50;
    float4 f;
    f.x = bf2f(tile[r4*4+0][c]);
    f.y = bf2f(tile[r4*4+1][c]);
    f.z = bf2f(tile[r4*4+2][c]);
    f.w = bf2f(tile[r4*4+3][c]);
    *((float4*)(on + (long)c * 1600 + r4 * 4)) = f;
  }
}

// ---------------- kernel B: fused compute v6 (4 waves, split QKV, banded no-max softmax) ----------------
// LDS (bytes):
//  RA 0..16383      : x tile image [64 t][256B] -> vT [128 d][128B] -> out staging image
//  RB 16384..49151  : per-head slot 8192B: {q|k} rows [64 t][128B] -> attn [64][128B] ; ao [64][136] ushorts after bar B
//  consts 49152..53759
#define B_RA    0
#define B_RB    16384
#define B_BQ    49152
#define B_BP    50688
#define B_RS    51200
#define B_SH    51712
#define B_BIAS  51728
#define B_TOTAL 53760

__global__ __launch_bounds__(256, 3) void fused_compute(
    const unsigned short* __restrict__ xb,
    const unsigned short* __restrict__ Wqkv,
    const unsigned short* __restrict__ Wp,
    const float* __restrict__ bqf,
    const float* __restrict__ bpf,
    const float* __restrict__ rsf,
    const float* __restrict__ shf,
    const float* __restrict__ relb,
    unsigned short* __restrict__ ob)
{
  __shared__ __align__(16) char smem[B_TOTAL];
  char* ra = smem + B_RA;
  float* c_bq   = (float*)(smem + B_BQ);
  float* c_bp   = (float*)(smem + B_BP);
  float* c_rs   = (float*)(smem + B_RS);
  float* c_sh   = (float*)(smem + B_SH);
  float* c_bias = (float*)(smem + B_BIAS);

  int bid = blockIdx.x;
  int swz = (bid & 7) * 800 + (bid >> 3);   // XCD-bijective (6400 % 8 == 0)
  long tileoff = (long)swz * 8192;          // ushort offset of 16KB tile
  int tid  = threadIdx.x;
  int lane = tid & 63;
  int w    = tid >> 6;
  int h    = w;                              // wave = head
  int l4   = lane >> 4;
  int l15  = lane & 15;

  char* qkh = smem + B_RB + h * 8192;        // [64 t][128B]: q bytes 0..63, k 64..127 (pre-XOR)

  // ---- phase 1: consts + x tile -> RA (coalesced b128) ----
  for (int i = tid; i < 384; i += 256) c_bq[i] = bqf[i];
  if (tid < 128){ c_bp[tid] = bpf[tid]; c_rs[tid] = rsf[tid]; }
  if (tid < 4) c_sh[tid] = shf[tid];
  for (int i = tid; i < 508; i += 256) c_bias[i] = relb[i];
  {
    const uint4* src = (const uint4*)(xb + tileoff);
    uint4* dst = (uint4*)ra;
    #pragma unroll
    for (int i = 0; i < 4; i++) dst[tid + i * 256] = src[tid + i * 256];
  }
  __syncthreads();   // bar A

  const f32x4 zero4 = {0.f, 0.f, 0.f, 0.f};
  uint2 resid[2][4];

  // ---- phase 2a: q/k GEMM (acc pressure 64 VGPRs), normalize, write to RB ----
  {
    int rb[4] = {32*h, 32*h + 16, 128 + 32*h, 128 + 32*h + 16};
    f32x4 acc[4][4];
    #pragma unroll
    for (int m = 0; m < 4; m++)
      #pragma unroll
      for (int nt = 0; nt < 4; nt++) acc[m][nt] = zero4;
    #pragma unroll
    for (int ks = 0; ks < 4; ks++){
      int ko = ks * 32 + l4 * 8;
      bf16x8 a[4], b[4];
      #pragma unroll
      for (int m = 0; m < 4; m++)
        a[m] = *((const bf16x8*)(Wqkv + (rb[m] + l15) * 128 + ko));
      #pragma unroll
      for (int nt = 0; nt < 4; nt++){
        int row = nt * 16 + l15;
        b[nt] = *((const bf16x8*)(ra + row * 256 + ((ko * 2) ^ ((row & 7) << 4))));
      }
      #pragma unroll
      for (int m = 0; m < 4; m++)
        #pragma unroll
        for (int nt = 0; nt < 4; nt++)
          acc[m][nt] = mfma16(a[m], b[nt], acc[m][nt]);
    }
    // bias (C layout: col t = l15, row = l4*4 + r within each 16-row tile)
    #pragma unroll
    for (int m = 0; m < 4; m++)
      #pragma unroll
      for (int nt = 0; nt < 4; nt++)
        #pragma unroll
        for (int r = 0; r < 4; r++)
          acc[m][nt][r] += c_bq[rb[m] + l4 * 4 + r];

    // in-register q/k normalization (sum over d via l4-group shuffle)
    #pragma unroll
    for (int nt = 0; nt < 4; nt++){
      float ssq = 0.f, ssk = 0.f;
      #pragma unroll
      for (int r = 0; r < 4; r++){
        ssq += acc[0][nt][r] * acc[0][nt][r] + acc[1][nt][r] * acc[1][nt][r];
        ssk += acc[2][nt][r] * acc[2][nt][r] + acc[3][nt][r] * acc[3][nt][r];
      }
      ssq += __shfl_xor(ssq, 16); ssq += __shfl_xor(ssq, 32);
      ssk += __shfl_xor(ssk, 16); ssk += __shfl_xor(ssk, 32);
      float scq = c_sh[h] / fmaxf(sqrtf(ssq), 1e-12f);
      float sck = 1.0f   / fmaxf(sqrtf(ssk), 1e-12f);
      int row = nt * 16 + l15;
      #pragma unroll
      for (int m = 0; m < 2; m++){
        uint2 p;
        p.x = pk2(acc[m][nt][0] * scq, acc[m][nt][1] * scq);
        p.y = pk2(acc[m][nt][2] * scq, acc[m][nt][3] * scq);
        *((uint2*)(qkh + row * 128 + ((m * 32 + l4 * 8) ^ ((row & 7) << 4)))) = p;
      }
      #pragma unroll
      for (int m = 2; m < 4; m++){
        uint2 p;
        p.x = pk2(acc[m][nt][0] * sck, acc[m][nt][1] * sck);
        p.y = pk2(acc[m][nt][2] * sck, acc[m][nt][3] * sck);
        *((uint2*)(qkh + row * 128 + ((64 + (m - 2) * 32 + l4 * 8) ^ ((row & 7) << 4)))) = p;
      }
    }
  }

  // ---- phase 2b: v GEMM (acc pressure 32 VGPRs) + resid extraction; vT overlays RA ----
  {
    int rb4 = 256 + 32 * h, rb5 = 256 + 32 * h + 16;
    f32x4 accv[2][4];
    #pragma unroll
    for (int m = 0; m < 2; m++)
      #pragma unroll
      for (int nt = 0; nt < 4; nt++) accv[m][nt] = zero4;
    #pragma unroll
    for (int ks = 0; ks < 4; ks++){
      int ko = ks * 32 + l4 * 8;
      bf16x8 a0 = *((const bf16x8*)(Wqkv + (rb4 + l15) * 128 + ko));
      bf16x8 a1 = *((const bf16x8*)(Wqkv + (rb5 + l15) * 128 + ko));
      #pragma unroll
      for (int nt = 0; nt < 4; nt++){
        int row = nt * 16 + l15;
        bf16x8 b = *((const bf16x8*)(ra + row * 256 + ((ko * 2) ^ ((row & 7) << 4))));
        accv[0][nt] = mfma16(a0, b, accv[0][nt]);
        accv[1][nt] = mfma16(a1, b, accv[1][nt]);
      }
    }
    // residual extraction (last RA reads) for this thread's phase-6 cells
    #pragma unroll
    for (int mt = 0; mt < 2; mt++)
      #pragma unroll
      for (int nt = 0; nt < 4; nt++){
        int o0 = w * 32 + mt * 16 + l4 * 4;
        int t2 = nt * 16 + l15;
        resid[mt][nt] = *((const uint2*)(ra + t2 * 256 + ((o0 * 2) ^ ((t2 & 7) << 4))));
      }
    __syncthreads();   // bar E: ALL RA reads done -> vT may overlay RA

    // write vT [128 d][128B] over RA, swizzled scalar b16 (with bias)
    #pragma unroll
    for (int m = 0; m < 2; m++)
      #pragma unroll
      for (int nt = 0; nt < 4; nt++)
        #pragma unroll
        for (int r = 0; r < 4; r++){
          int d = h * 32 + m * 16 + l4 * 4 + r;
          float vv = accv[m][nt][r] + c_bq[256 + h * 32 + m * 16 + l4 * 4 + r];
          *((unsigned short*)(ra + d * 128 + ((((nt * 16 + l15) * 2)) ^ ((d & 7) << 4)))) = f2bf(vv);
        }
  }
  __builtin_amdgcn_sched_barrier(0);   // wave-private LDS RAW fence

  // ---- phase 4: score fragments (own-wave LDS, DS in-order per wave) ----
  bf16x8 kf[4], qf[4];
  {
    #pragma unroll
    for (int jt = 0; jt < 4; jt++){
      int row = jt * 16 + l15;
      kf[jt] = *((const bf16x8*)(qkh + row * 128 + ((64 + l4 * 16) ^ ((row & 7) << 4))));
    }
    #pragma unroll
    for (int it = 0; it < 4; it++){
      int row = it * 16 + l15;
      qf[it] = *((const bf16x8*)(qkh + row * 128 + ((l4 * 16) ^ ((row & 7) << 4))));
    }
  }
  __builtin_amdgcn_sched_barrier(0);

  // ---- phase 5a: banded scores^T = K·Q^T (|jt-it|<=1 only), no-max softmax ----
  // justification: q,k are L2-normalized, |score| <= c_sh (<=17.7 capped) + |bias| -> fp32 exp safe;
  // exp(s)/sum(exp(s)) == softmax exactly.
  {
    f32x4 sAcc[4][4];
    #pragma unroll
    for (int jt = 0; jt < 4; jt++)
      #pragma unroll
      for (int it = 0; it < 4; it++) sAcc[jt][it] = zero4;
    #pragma unroll
    for (int jt = 0; jt < 4; jt++)
      #pragma unroll
      for (int it = 0; it < 4; it++)
        if (jt <= it + 1 && it <= jt + 1)
          sAcc[jt][it] = mfma16(kf[jt], qf[it], sAcc[jt][it]);

    #pragma unroll
    for (int it = 0; it < 4; it++){
      int i = it * 16 + l15;
      float sv[16];
      float sum = 0.f;
      #pragma unroll
      for (int jt = 0; jt < 4; jt++){
        if (jt + 1 < it || jt > it + 1) continue;   // fully-masked tile
        #pragma unroll
        for (int r = 0; r < 4; r++){
          int j = jt * 16 + l4 * 4 + r;
          int rel = j - i;
          float s = sAcc[jt][it][r] + c_bias[h * 127 + rel + 63];  // idx in [32,94]+h*127: in bounds
          bool inb = (rel >= -4) && (rel <= 4);
          float p = inb ? __expf(s) : 0.f;
          sv[jt * 4 + r] = p;
          sum += p;
        }
      }
      sum += __shfl_xor(sum, 16);
      sum += __shfl_xor(sum, 32);
      float rs = 1.0f / sum;
      #pragma unroll
      for (int jt = 0; jt < 4; jt++){
        uint2 p;
        if (jt + 1 < it || jt > it + 1){
          p.x = 0u; p.y = 0u;
        } else {
          p.x = pk2(sv[jt*4+0] * rs, sv[jt*4+1] * rs);
          p.y = pk2(sv[jt*4+2] * rs, sv[jt*4+3] * rs);
        }
        *((uint2*)(qkh + i * 128 + ((jt * 32 + l4 * 8) ^ ((i & 7) << 4)))) = p;
      }
    }
  }
  __builtin_amdgcn_sched_barrier(0);

  // ---- PV fragments (own attn rows + own vT rows) ----
  bf16x8 av[2][2], bv2[4][2];
  {
    #pragma unroll
    for (int mt = 0; mt < 2; mt++)
      #pragma unroll
      for (int ks2 = 0; ks2 < 2; ks2++){
        int row = h * 32 + mt * 16 + l15;
        av[mt][ks2] = *((const bf16x8*)(ra + row * 128 + ((ks2 * 64 + l4 * 16) ^ ((row & 7) << 4))));
      }
    #pragma unroll
    for (int it = 0; it < 4; it++)
      #pragma unroll
      for (int ks2 = 0; ks2 < 2; ks2++){
        int row = it * 16 + l15;
        bv2[it][ks2] = *((const bf16x8*)(qkh + row * 128 + ((ks2 * 64 + l4 * 16) ^ ((row & 7) << 4))));
      }
  }
  __syncthreads();   // bar B: all attn/vT-for-PV reads done -> ao may overwrite RB

  // ---- phase 5b: ao[t][c] = (val^T · attn^T)^T ----
  unsigned short* ao = (unsigned short*)(smem + B_RB);   // [64][136]
  {
    f32x4 pAcc[2][4];
    #pragma unroll
    for (int mt = 0; mt < 2; mt++)
      #pragma unroll
      for (int it = 0; it < 4; it++) pAcc[mt][it] = zero4;
    #pragma unroll
    for (int mt = 0; mt < 2; mt++)
      #pragma unroll
      for (int it = 0; it < 4; it++)
        #pragma unroll
        for (int ks2 = 0; ks2 < 2; ks2++)
          pAcc[mt][it] = mfma16(av[mt][ks2], bv2[it][ks2], pAcc[mt][it]);
    #pragma unroll
    for (int mt = 0; mt < 2; mt++)
      #pragma unroll
      for (int it = 0; it < 4; it++){
        int d0 = mt * 16 + l4 * 4;
        int i  = it * 16 + l15;
        uint2 p;
        p.x = pk2(pAcc[mt][it][0], pAcc[mt][it][1]);
        p.y = pk2(pAcc[mt][it][2], pAcc[mt][it][3]);
        *((uint2*)&ao[i * 136 + h * 32 + d0]) = p;
      }
  }
  __syncthreads();   // bar C: ao complete

  // ---- phase 6: proj GEMM + residual(regs) + out-BN, stage into RA image, copy out ----
  {
    f32x4 acc2[2][4];
    #pragma unroll
    for (int mt = 0; mt < 2; mt++)
      #pragma unroll
      for (int nt = 0; nt < 4; nt++) acc2[mt][nt] = zero4;
    #pragma unroll
    for (int ks = 0; ks < 4; ks++){
      int ko = ks * 32 + l4 * 8;
      bf16x8 a2[2], b2[4];
      #pragma unroll
      for (int mt = 0; mt < 2; mt++)
        a2[mt] = *((const bf16x8*)(Wp + (w * 32 + mt * 16 + l15) * 128 + ko));
      #pragma unroll
      for (int nt = 0; nt < 4; nt++)
        b2[nt] = *((const bf16x8*)&ao[(nt * 16 + l15) * 136 + ko]);
      #pragma unroll
      for (int mt = 0; mt < 2; mt++)
        #pragma unroll
        for (int nt = 0; nt < 4; nt++)
          acc2[mt][nt] = mfma16(a2[mt], b2[nt], acc2[mt][nt]);
    }
    #pragma unroll
    for (int mt = 0; mt < 2; mt++)
      #pragma unroll
      for (int nt = 0; nt < 4; nt++){
        int o0 = w * 32 + mt * 16 + l4 * 4;
        int t2 = nt * 16 + l15;
        uint2 rd = resid[mt][nt];
        float r0 = bf2f((unsigned short)(rd.x & 0xFFFFu));
        float r1f = bf2f((unsigned short)(rd.x >> 16));
        float r2 = bf2f((unsigned short)(rd.y & 0xFFFFu));
        float r3 = bf2f((unsigned short)(rd.y >> 16));
        uint2 p;
        p.x = pk2(acc2[mt][nt][0] + c_bp[o0+0] + r0 * c_rs[o0+0],
                  acc2[mt][nt][1] + c_bp[o0+1] + r1f * c_rs[o0+1]);
        p.y = pk2(acc2[mt][nt][2] + c_bp[o0+2] + r2 * c_rs[o0+2],
                  acc2[mt][nt][3] + c_bp[o0+3] + r3 * c_rs[o0+3]);
        *((uint2*)(ra + t2 * 256 + ((o0 * 2) ^ ((t2 & 7) << 4)))) = p;
      }
  }
  __syncthreads();   // bar D
  {
    const uint4* sxl = (const uint4*)ra;
    uint4* obt = (uint4*)(ob + tileoff);
    #pragma unroll
    for (int i = 0; i < 4; i++) obt[tid + i * 256] = sxl[tid + i * 256];
  }
}

// ---------------- fallback: fused scatter kernel (ws too small) ----------------
#define F_X     0
#define F_RB    17408
#define F_VT    58368
#define F_BQ    76800
#define F_BP    78336
#define F_RS    78848
#define F_SH    79360
#define F_BIAS  79376
#define F_TOTAL 81408

__global__ __launch_bounds__(256, 2) void fused_scatter(
    const float* __restrict__ x,
    const unsigned short* __restrict__ Wqkv,
    const unsigned short* __restrict__ Wp,
    const float* __restrict__ bqf,
    const float* __restrict__ bpf,
    const float* __restrict__ rsf,
    const float* __restrict__ shf,
    const float* __restrict__ relb,
    float* __restrict__ out)
{
  __shared__ __align__(16) char smem[F_TOTAL];
  unsigned short* xl   = (unsigned short*)(smem + F_X);
  unsigned short* rbu  = (unsigned short*)(smem + F_RB);
  unsigned short* vT   = (unsigned short*)(smem + F_VT);
  float* c_bq   = (float*)(smem + F_BQ);
  float* c_bp   = (float*)(smem + F_BP);
  float* c_rs   = (float*)(smem + F_RS);
  float* c_sh   = (float*)(smem + F_SH);
  float* c_bias = (float*)(smem + F_BIAS);

  int bid = blockIdx.x;
  int swz = (bid & 7) * 800 + (bid >> 3);
  int n = swz / 25;
  int v = swz - n * 25;
  int tid  = threadIdx.x;
  int lane = tid & 63;
  int w    = tid >> 6;
  int l4   = lane >> 4;
  int l15  = lane & 15;

  for (int i = tid; i < 384; i += 256) c_bq[i] = bqf[i];
  if (tid < 128){ c_bp[tid] = bpf[tid]; c_rs[tid] = rsf[tid]; }
  if (tid < 4) c_sh[tid] = shf[tid];
  for (int i = tid; i < 508; i += 256) c_bias[i] = relb[i];

  {
    const float* xb2 = x + (long)n * 204800 + v;
    int t  = lane;
    int cg = w * 32;
    #pragma unroll
    for (int i = 0; i < 4; i++){
      unsigned int pk[4];
      #pragma unroll
      for (int e = 0; e < 4; e++){
        int c = cg + i * 8 + e * 2;
        pk[e] = pk2(xb2[(long)c * 1600 + t * 25], xb2[(long)(c + 1) * 1600 + t * 25]);
      }
      uint4 q4; q4.x = pk[0]; q4.y = pk[1]; q4.z = pk[2]; q4.w = pk[3];
      *((uint4*)&xl[t * 136 + cg + i * 8]) = q4;
    }
  }
  __syncthreads();

  const f32x4 zero4 = {0.f, 0.f, 0.f, 0.f};

  {
    f32x4 acc[6][4];
    #pragma unroll
    for (int m = 0; m < 6; m++)
      #pragma unroll
      for (int nt = 0; nt < 4; nt++) acc[m][nt] = zero4;
    int Mb = w * 96;
    #pragma unroll
    for (int ks = 0; ks < 4; ks++){
      int ko = ks * 32 + l4 * 8;
      bf16x8 a[6], b[4];
      #pragma unroll
      for (int m = 0; m < 6; m++)
        a[m] = *((const bf16x8*)(Wqkv + (Mb + m * 16 + l15) * 128 + ko));
      #pragma unroll
      for (int nt = 0; nt < 4; nt++)
        b[nt] = *((const bf16x8*)&xl[(nt * 16 + l15) * 136 + ko]);
      #pragma unroll
      for (int m = 0; m < 6; m++)
        #pragma unroll
        for (int nt = 0; nt < 4; nt++)
          acc[m][nt] = mfma16(a[m], b[nt], acc[m][nt]);
    }
    #pragma unroll
    for (int m = 0; m < 6; m++){
      #pragma unroll
      for (int nt = 0; nt < 4; nt++){
        #pragma unroll
        for (int r = 0; r < 4; r++){
          int o  = Mb + m * 16 + l4 * 4 + r;
          int t2 = nt * 16 + l15;
          unsigned short bv = f2bf(acc[m][nt][r] + c_bq[o]);
          if (o < 256){
            rbu[(((o >> 7) * 4 + ((o >> 5) & 3)) * 64 + t2) * 40 + (o & 31)] = bv;
          } else {
            vT[(o - 256) * 72 + t2] = bv;
          }
        }
      }
    }
  }
  __syncthreads();

  {
    #pragma unroll
    for (int rr = 0; rr < 2; rr++){
      int r = tid + rr * 256;
      unsigned short* row = &rbu[r * 40];
      uint4 u0 = *((uint4*)(row + 0));
      uint4 u1 = *((uint4*)(row + 8));
      uint4 u2 = *((uint4*)(row + 16));
      uint4 u3 = *((uint4*)(row + 24));
      unsigned int uu[16] = {u0.x,u0.y,u0.z,u0.w, u1.x,u1.y,u1.z,u1.w,
                             u2.x,u2.y,u2.z,u2.w, u3.x,u3.y,u3.z,u3.w};
      float vals[32];
      float ss = 0.f;
      #pragma unroll
      for (int k2 = 0; k2 < 16; k2++){
        float f0 = bf2f((unsigned short)(uu[k2] & 0xFFFFu));
        float f1 = bf2f((unsigned short)(uu[k2] >> 16));
        vals[2*k2] = f0; vals[2*k2+1] = f1;
        ss += f0 * f0 + f1 * f1;
      }
      float sc = 1.0f / fmaxf(sqrtf(ss), 1e-12f);
      if (r < 256) sc *= c_sh[(r >> 6) & 3];
      #pragma unroll
      for (int k2 = 0; k2 < 16; k2++)
        uu[k2] = pk2(vals[2*k2] * sc, vals[2*k2+1] * sc);
      u0.x=uu[0];u0.y=uu[1];u0.z=uu[2];u0.w=uu[3];
      u1.x=uu[4];u1.y=uu[5];u1.z=uu[6];u1.w=uu[7];
      u2.x=uu[8];u2.y=uu[9];u2.z=uu[10];u2.w=uu[11];
      u3.x=uu[12];u3.y=uu[13];u3.z=uu[14];u3.w=uu[15];
      *((uint4*)(row + 0))  = u0;
      *((uint4*)(row + 8))  = u1;
      *((uint4*)(row + 16)) = u2;
      *((uint4*)(row + 24)) = u3;
    }
  }
  __syncthreads();

  int h = w;
  bf16x8 kf[4], qf[4];
  {
    const unsigned short* kb = &rbu[(256 + h * 64) * 40];
    const unsigned short* qb = &rbu[(h * 64) * 40];
    int ko = l4 * 8;
    #pragma unroll
    for (int jt = 0; jt < 4; jt++)
      kf[jt] = *((const bf16x8*)(kb + (jt * 16 + l15) * 40 + ko));
    #pragma unroll
    for (int it = 0; it < 4; it++)
      qf[it] = *((const bf16x8*)(qb + (it * 16 + l15) * 40 + ko));
  }
  __syncthreads();

  unsigned short* attn = rbu + h * 4608;
  {
    f32x4 sAcc[4][4];
    #pragma unroll
    for (int jt = 0; jt < 4; jt++)
      #pragma unroll
      for (int it = 0; it < 4; it++) sAcc[jt][it] = zero4;
    #pragma unroll
    for (int jt = 0; jt < 4; jt++)
      #pragma unroll
      for (int it = 0; it < 4; it++)
        sAcc[jt][it] = mfma16(kf[jt], qf[it], sAcc[jt][it]);

    #pragma unroll
    for (int it = 0; it < 4; it++){
      int i = it * 16 + l15;
      float sv[16];
      float mx = -1e30f;
      #pragma unroll
      for (int jt = 0; jt < 4; jt++){
        #pragma unroll
        for (int r = 0; r < 4; r++){
          int j = jt * 16 + l4 * 4 + r;
          int rel = j - i;
          float s;
          if (rel < -4 || rel > 4) s = -1e9f;
          else s = sAcc[jt][it][r] + c_bias[h * 127 + rel + 63];
          sv[jt * 4 + r] = s;
          mx = fmaxf(mx, s);
        }
      }
      mx = fmaxf(mx, __shfl_xor(mx, 16));
      mx = fmaxf(mx, __shfl_xor(mx, 32));
      float sum = 0.f;
      #pragma unroll
      for (int k2 = 0; k2 < 16; k2++){
        float p = __expf(sv[k2] - mx);
        sv[k2] = p; sum += p;
      }
      sum += __shfl_xor(sum, 16);
      sum += __shfl_xor(sum, 32);
      float rs = 1.0f / sum;
      #pragma unroll
      for (int jt = 0; jt < 4; jt++)
        #pragma unroll
        for (int r = 0; r < 4; r++)
          attn[i * 72 + (jt * 16 + l4 * 4 + r)] = f2bf(sv[jt * 4 + r] * rs);
    }
  }

  bf16x8 av[2][2], bv2[4][2];
  {
    int ko = l4 * 8;
    #pragma unroll
    for (int mt = 0; mt < 2; mt++)
      #pragma unroll
      for (int ks2 = 0; ks2 < 2; ks2++)
        av[mt][ks2] = *((const bf16x8*)&vT[(h * 32 + mt * 16 + l15) * 72 + ks2 * 32 + ko]);
    #pragma unroll
    for (int it = 0; it < 4; it++)
      #pragma unroll
      for (int ks2 = 0; ks2 < 2; ks2++)
        bv2[it][ks2] = *((const bf16x8*)&attn[(it * 16 + l15) * 72 + ks2 * 32 + ko]);
  }
  __syncthreads();

  unsigned short* ao = rbu;
  {
    f32x4 pAcc[2][4];
    #pragma unroll
    for (int mt = 0; mt < 2; mt++)
      #pragma unroll
      for (int it = 0; it < 4; it++) pAcc[mt][it] = zero4;
    #pragma unroll
    for (int mt = 0; mt < 2; mt++)
      #pragma unroll
      for (int it = 0; it < 4; it++)
        #pragma unroll
        for (int ks2 = 0; ks2 < 2; ks2++)
          pAcc[mt][it] = mfma16(av[mt][ks2], bv2[it][ks2], pAcc[mt][it]);
    #pragma unroll
    for (int mt = 0; mt < 2; mt++)
      #pragma unroll
      for (int it = 0; it < 4; it++)
        #pragma unroll
        for (int r = 0; r < 4; r++){
          int d = mt * 16 + l4 * 4 + r;
          int i = it * 16 + l15;
          ao[i * 136 + h * 32 + d] = f2bf(pAcc[mt][it][r]);
        }
  }
  __syncthreads();

  {
    f32x4 acc2[2][4];
    #pragma unroll
    for (int mt = 0; mt < 2; mt++)
      #pragma unroll
      for (int nt = 0; nt < 4; nt++) acc2[mt][nt] = zero4;
    #pragma unroll
    for (int ks = 0; ks < 4; ks++){
      int ko = ks * 32 + l4 * 8;
      bf16x8 a2[2], b2[4];
      #pragma unroll
      for (int mt = 0; mt < 2; mt++)
        a2[mt] = *((const bf16x8*)(Wp + (w * 32 + mt * 16 + l15) * 128 + ko));
      #pragma unroll
      for (int nt = 0; nt < 4; nt++)
        b2[nt] = *((const bf16x8*)&ao[(nt * 16 + l15) * 136 + ko]);
      #pragma unroll
      for (int mt = 0; mt < 2; mt++)
        #pragma unroll
        for (int nt = 0; nt < 4; nt++)
          acc2[mt][nt] = mfma16(a2[mt], b2[nt], acc2[mt][nt]);
    }
    float* outp = out + (long)n * 204800 + v;
    #pragma unroll
    for (int mt = 0; mt < 2; mt++)
      #pragma unroll
      for (int nt = 0; nt < 4; nt++)
        #pragma unroll
        for (int r = 0; r < 4; r++){
          int o  = w * 32 + mt * 16 + l4 * 4 + r;
          int t2 = nt * 16 + l15;
          float val = acc2[mt][nt][r] + c_bp[o] + bf2f(xl[t2 * 136 + o]) * c_rs[o];
          outp[(long)o * 1600 + t2 * 25] = val;
        }
  }
}

// ---------------- launcher ----------------
extern "C" void kernel_launch(void* const* d_in, const int* in_sizes, int n_in,
                              void* d_out, int out_size, void* d_ws, size_t ws_size,
                              hipStream_t stream)
{
  const float* x     = (const float*)d_in[0];
  const float* bn_g  = (const float*)d_in[1];
  const float* bn_b  = (const float*)d_in[2];
  const float* bn_m  = (const float*)d_in[3];
  const float* bn_v  = (const float*)d_in[4];
  const float* qk_w  = (const float*)d_in[5];
  const float* qk_b  = (const float*)d_in[6];
  const float* v_w   = (const float*)d_in[7];
  const float* v_b   = (const float*)d_in[8];
  const float* ls    = (const float*)d_in[9];
  const float* relb  = (const float*)d_in[10];
  const float* pj_w  = (const float*)d_in[11];
  const float* pj_b  = (const float*)d_in[12];
  const float* bo_g  = (const float*)d_in[13];
  const float* bo_b  = (const float*)d_in[14];
  const float* bo_m  = (const float*)d_in[15];
  const float* bo_v  = (const float*)d_in[16];

  const size_t XB_BYTES = 104857600;   // 6400 * 16384
  const size_t NEED = 2 * XB_BYTES + 98304 + 32768 + 1536 + 512 + 512 + 16;

  char* ws = (char*)d_ws;
  size_t wbase = (ws_size >= NEED) ? (2 * XB_BYTES) : 0;

  unsigned short* Wqkv = (unsigned short*)(ws + wbase);
  unsigned short* Wp   = (unsigned short*)(ws + wbase + 98304);
  float* bqf = (float*)(ws + wbase + 131072);
  float* bpf = (float*)(ws + wbase + 132608);
  float* rsf = (float*)(ws + wbase + 133120);
  float* shf = (float*)(ws + wbase + 133632);

  if (ws_size >= NEED){
    unsigned short* xb = (unsigned short*)(ws);
    unsigned short* ob = (unsigned short*)(ws + XB_BYTES);
    // prep merged into pack_x (blocks 0,1)
    hipLaunchKernelGGL(pack_x, dim3(2048), dim3(256), 0, stream, x, xb,
                       bn_g, bn_b, bn_m, bn_v, qk_w, qk_b, v_w, v_b, ls,
                       pj_w, pj_b, bo_g, bo_b, bo_m, bo_v,
                       Wqkv, Wp, bqf, bpf, rsf, shf);
    hipLaunchKernelGGL(fused_compute, dim3(6400), dim3(256), 0, stream,
                       xb, Wqkv, Wp, bqf, bpf, rsf, shf, relb, ob);
    hipLaunchKernelGGL(unpack_out, dim3(2048), dim3(256), 0, stream, ob, (float*)d_out);
  } else {
    hipLaunchKernelGGL(prep_kernel, dim3(2), dim3(256), 0, stream,
                       bn_g, bn_b, bn_m, bn_v, qk_w, qk_b, v_w, v_b, ls,
                       pj_w, pj_b, bo_g, bo_b, bo_m, bo_v,
                       Wqkv, Wp, bqf, bpf, rsf, shf);
    hipLaunchKernelGGL(fused_scatter, dim3(6400), dim3(256), 0, stream,
                       x, Wqkv, Wp, bqf, bpf, rsf, shf, relb, (float*)d_out);
  }
}